// Round 2
// baseline (268.952 us; speedup 1.0000x reference)
//
#include <hip/hip_runtime.h>
#include <cmath>

#define NQ 16
#define NT 8

typedef float f32x4 __attribute__((ext_vector_type(4)));

// order-preserving float->u32 (total order ascending)
__device__ __forceinline__ unsigned ordf(float x) {
    unsigned u = __float_as_uint(x);
    return u ^ ((unsigned)((int)u >> 31) | 0x80000000u);
}
// inverse; 0xFFFFFFFF (empty sentinel) -> NaN so ordered compares are false
__device__ __forceinline__ float unordf(unsigned k) {
    unsigned m = (~(unsigned)((int)k >> 31)) | 0x80000000u;
    return __uint_as_float(k ^ m);
}
__device__ __forceinline__ unsigned umin2(unsigned a, unsigned b) { return a < b ? a : b; }
__device__ __forceinline__ unsigned umax2(unsigned a, unsigned b) { return a > b ? a : b; }
__device__ __forceinline__ unsigned umin3(unsigned a, unsigned b, unsigned c) {
    return umin2(umin2(a, b), c);   // -> v_min3_u32
}

// Intra-quad lane exchange via DPP quad_perm — single VALU op, no LDS pipe,
// no lgkmcnt wait. Replaces __shfl_xor(...,r,4) which lowers to ds_bpermute.
// xor1: [1,0,3,2] = 0xB1;  xor2: [2,3,0,1] = 0x4E.
__device__ __forceinline__ unsigned dpp_xor1_u(unsigned x) {
    return (unsigned)__builtin_amdgcn_mov_dpp((int)x, 0xB1, 0xF, 0xF, true);
}
__device__ __forceinline__ unsigned dpp_xor2_u(unsigned x) {
    return (unsigned)__builtin_amdgcn_mov_dpp((int)x, 0x4E, 0xF, 0xF, true);
}
__device__ __forceinline__ float dpp_xor1_f(float x) {
    return __uint_as_float(dpp_xor1_u(__float_as_uint(x)));
}

// Exact reference-parity path (rare): recompute the whole row with the
// correctly-rounded double-exp sigmoid and exact float dedup (validated
// bit-exact vs reference, absmax 0.0). Unchanged.
__device__ __noinline__ unsigned exact_mask(
    const float* __restrict__ pred_logits,
    const float* __restrict__ pred_disp,
    const float* __restrict__ targets,
    size_t b)
{
    float tg[NT];
#pragma unroll
    for (int t = 0; t < NT; ++t) {
        float v = targets[b * NT + t];
        tg[t] = (v == 0.0f) ? 1000000.0f : v;
    }
    float C[NQ];
    int   ind[NQ];
#pragma unroll
    for (int n = 0; n < NQ; ++n) {
        float d = pred_disp[b * NQ + n];
        float best = fabsf(d - tg[0]);
        int bi = 0;
#pragma unroll
        for (int t = 1; t < NT; ++t) {
            float e = fabsf(d - tg[t]);
            if (e < best) { best = e; bi = t; }   // strict <: first target wins
        }
        float sig = (float)(1.0 / (1.0 + exp(-(double)pred_logits[b * NQ + n])));
        C[n] = (-sig) + best;                     // same op order as reference
        ind[n] = bi;
    }
    unsigned mask = 0u;
#pragma unroll
    for (int t = 0; t < NT; ++t) {
        int w = 31;
        float bc = 3.0e38f;
#pragma unroll
        for (int n = 0; n < NQ; ++n) {
            bool upd = (ind[n] == t) && (C[n] < bc);  // strict <: first query wins
            bc = upd ? C[n] : bc;
            w  = upd ? n : w;
        }
        mask |= (1u << w);
    }
    return mask;
}

// FOUR lanes per row (proven layout: every global load/store is 16 B/lane
// perfectly contiguous — 16 cache lines per wave instruction). Lane j of a
// quad owns queries 4j..4j+3.
//
// Dedup is a SPLIT-OWNERSHIP butterfly: after the local (per-lane) pass over
// 8 targets, butterfly round 1 (DPP xor1) merges pairs and each lane KEEPS
// only 4 targets (parity-selected, static indices); round 2 (DPP xor2)
// merges and keeps 2. Guard + mask are then evaluated for only 2 targets per
// lane (vs 8 replicated in all lanes before), and a 2-step DPP OR-reduce
// (mask bits 0..15 | need_slow in bit 30) broadcasts the combined word.
// The (min,2nd-min) tournament merge is associative -> per-target bc/bc2 are
// bit-identical to the replicated version -> identical guard decisions.
__global__ __launch_bounds__(256) void nearest_matcher_kernel(
    const float* __restrict__ pred_logits,
    const float* __restrict__ pred_disp,
    const float* __restrict__ targets,
    float* __restrict__ out_idx,
    float* __restrict__ out_lab,
    int B)
{
    const size_t gid = (size_t)blockIdx.x * blockDim.x + threadIdx.x;
    const size_t b   = gid >> 2;          // row
    const int    j   = (int)(gid & 3);    // lane-in-quad: owns queries 4j..4j+3
    if (b >= (size_t)B) return;

    const float BIGF = 1000000.0f;

    // ---- coalesced loads: 16 B/lane, consecutive lanes consecutive addrs ----
    f32x4 d4 = ((const f32x4*)pred_disp)[gid];
    f32x4 l4 = ((const f32x4*)pred_logits)[gid];
    f32x4 t4 = ((const f32x4*)targets)[b * 2 + (size_t)(j & 1)];  // half (j&1)

    // sentinel-replace my half, then swap halves across lane^1 (DPP)
    float tv[4] = {t4.x, t4.y, t4.z, t4.w};
#pragma unroll
    for (int i = 0; i < 4; ++i) tv[i] = (tv[i] == 0.0f) ? BIGF : tv[i];
    float ov[4];
#pragma unroll
    for (int i = 0; i < 4; ++i) ov[i] = dpp_xor1_f(tv[i]);

    float tg[NT];
#pragma unroll
    for (int i = 0; i < 4; ++i) {
        tg[i]     = ((j & 1) == 0) ? tv[i] : ov[i];
        tg[4 + i] = ((j & 1) == 0) ? ov[i] : tv[i];
    }

    // ---- my 4 queries: exact argmin over 8 targets + fast-sigmoid key ----
    int      ind[4];
    unsigned qk[4];
    {
        float dv[4] = {d4.x, d4.y, d4.z, d4.w};
        float lv[4] = {l4.x, l4.y, l4.z, l4.w};
#pragma unroll
        for (int i = 0; i < 4; ++i) {
            float d = dv[i];
            float best = fabsf(d - tg[0]);
            int bi = 0;
#pragma unroll
            for (int t = 1; t < NT; ++t) {
                float e = fabsf(d - tg[t]);
                if (e < best) { best = e; bi = t; }   // exact: matches reference
            }
            ind[i] = bi;
            float sig = __builtin_amdgcn_rcpf(1.0f + __expf(-lv[i]));
            float C = best - sig;
            int n = 4 * j + i;                        // global query id
            qk[i] = (ordf(C) & ~31u) | (unsigned)n;   // key: C order + query id
        }
    }

    // ---- local per-target (best, 2nd-best) over my 4 queries ----
    unsigned lb[NT], lb2[NT];
#pragma unroll
    for (int t = 0; t < NT; ++t) {
        unsigned bc = 0xFFFFFFFFu, bc2 = 0xFFFFFFFFu;
#pragma unroll
        for (int i = 0; i < 4; ++i) {
            unsigned x = (ind[i] == t) ? qk[i] : 0xFFFFFFFFu;
            unsigned hi = umax2(bc, x);
            bc  = umin2(bc, x);
            bc2 = umin2(bc2, hi);
        }
        lb[t] = bc; lb2[t] = bc2;
    }

    // ---- butterfly round 1 (lane^1), keep 4 targets by parity j&1 ----
    unsigned ka[4], ka2[4];
    {
        unsigned mA[NT], mA2[NT];
#pragma unroll
        for (int t = 0; t < NT; ++t) {
            unsigned ob  = dpp_xor1_u(lb[t]);
            unsigned ob2 = dpp_xor1_u(lb2[t]);
            unsigned hi  = umax2(lb[t], ob);
            mA[t]  = umin2(lb[t], ob);
            mA2[t] = umin3(lb2[t], ob2, hi);
        }
        const bool p1 = (j & 1) != 0;
#pragma unroll
        for (int u = 0; u < 4; ++u) {
            ka[u]  = p1 ? mA[u + 4]  : mA[u];
            ka2[u] = p1 ? mA2[u + 4] : mA2[u];
        }
    }

    // ---- butterfly round 2 (lane^2; partner has same j&1), keep 2 ----
    unsigned fb[2], fb2[2];
    {
        unsigned mB[4], mB2[4];
#pragma unroll
        for (int u = 0; u < 4; ++u) {
            unsigned ob  = dpp_xor2_u(ka[u]);
            unsigned ob2 = dpp_xor2_u(ka2[u]);
            unsigned hi  = umax2(ka[u], ob);
            mB[u]  = umin2(ka[u], ob);
            mB2[u] = umin3(ka2[u], ob2, hi);
        }
        const bool p2 = (j & 2) != 0;
#pragma unroll
        for (int v = 0; v < 2; ++v) {
            fb[v]  = p2 ? mB[v + 2]  : mB[v];
            fb2[v] = p2 ? mB2[v + 2] : mB2[v];
        }
    }

    // ---- guard + mask for my 2 owned targets, then OR-reduce over quad ----
    unsigned w = 0u;
    {
        bool ns = false;
#pragma unroll
        for (int v = 0; v < 2; ++v) {
            // guard in float domain; empty/singleton -> NaN -> compare false.
            // thr covers fast-sigmoid error + 5-bit key clearing at all C scales.
            float bcf  = unordf(fb[v]);
            float bc2f = unordf(fb2[v]);
            float thr  = fmaf(fabsf(bcf), 1.6e-5f, 2.0e-4f);
            ns = ns || ((bc2f - bcf) < thr);
            w |= (1u << (fb[v] & 31u));   // empty -> bit 31, ignored below
        }
        if (ns) w |= 0x40000000u;          // need_slow flag in bit 30
        w |= dpp_xor1_u(w);
        w |= dpp_xor2_u(w);
    }
    unsigned mask = w;                     // bits 0..15 = labels in query order

    // whole quad agrees (OR-reduced word identical) -> no intra-quad divergence
    if (__builtin_expect((w & 0x40000000u) != 0u, 0))
        mask = exact_mask(pred_logits, pred_disp, targets, b);

    // ---- emit my 4 queries: 16 B/lane contiguous ----
    f32x4 oi, ol;
    oi.x = (float)ind[0]; oi.y = (float)ind[1];
    oi.z = (float)ind[2]; oi.w = (float)ind[3];
    ol.x = (float)((mask >> (4 * j + 0)) & 1u);
    ol.y = (float)((mask >> (4 * j + 1)) & 1u);
    ol.z = (float)((mask >> (4 * j + 2)) & 1u);
    ol.w = (float)((mask >> (4 * j + 3)) & 1u);
    ((f32x4*)out_idx)[gid] = oi;
    ((f32x4*)out_lab)[gid] = ol;
}

extern "C" void kernel_launch(void* const* d_in, const int* in_sizes, int n_in,
                              void* d_out, int out_size, void* d_ws, size_t ws_size,
                              hipStream_t stream) {
    const float* pred_logits = (const float*)d_in[0];
    const float* pred_disp   = (const float*)d_in[1];
    const float* targets     = (const float*)d_in[2];

    int B = in_sizes[0] / NQ;

    float* out_idx = (float*)d_out;              // indices [B, NQ] flat, first
    float* out_lab = out_idx + (size_t)B * NQ;   // labels  [B, NQ] flat, second

    const int threads = 256;
    const size_t total = (size_t)B * 4;          // 4 lanes per row
    const int blocks = (int)((total + threads - 1) / threads);
    hipLaunchKernelGGL(nearest_matcher_kernel, dim3(blocks), dim3(threads), 0, stream,
                       pred_logits, pred_disp, targets, out_idx, out_lab, B);
}

// Round 3
// 256.222 us; speedup vs baseline: 1.0497x; 1.0497x over previous
//
#include <hip/hip_runtime.h>
#include <cmath>

#define NQ 16
#define NT 8

typedef float f32x4 __attribute__((ext_vector_type(4)));

// order-preserving float->u32 (total order ascending)
__device__ __forceinline__ unsigned ordf(float x) {
    unsigned u = __float_as_uint(x);
    return u ^ ((unsigned)((int)u >> 31) | 0x80000000u);
}
// inverse (keys here are always real query keys, never the empty sentinel)
__device__ __forceinline__ float unordf(unsigned k) {
    unsigned m = (~(unsigned)((int)k >> 31)) | 0x80000000u;
    return __uint_as_float(k ^ m);
}
__device__ __forceinline__ unsigned umin2(unsigned a, unsigned b) { return a < b ? a : b; }

// Intra-quad lane exchange via DPP quad_perm — single VALU op, no LDS pipe,
// no lgkmcnt wait. Replaces __shfl_xor(...,r,4) which lowers to ds_bpermute.
// xor1: [1,0,3,2] = 0xB1;  xor2: [2,3,0,1] = 0x4E.
__device__ __forceinline__ unsigned dpp_xor1_u(unsigned x) {
    return (unsigned)__builtin_amdgcn_mov_dpp((int)x, 0xB1, 0xF, 0xF, true);
}
__device__ __forceinline__ unsigned dpp_xor2_u(unsigned x) {
    return (unsigned)__builtin_amdgcn_mov_dpp((int)x, 0x4E, 0xF, 0xF, true);
}
__device__ __forceinline__ float dpp_xor1_f(float x) {
    return __uint_as_float(dpp_xor1_u(__float_as_uint(x)));
}

// Exact reference-parity path (rare): recompute the whole row with the
// correctly-rounded double-exp sigmoid and exact float dedup (validated
// bit-exact vs reference, absmax 0.0). Unchanged.
__device__ __noinline__ unsigned exact_mask(
    const float* __restrict__ pred_logits,
    const float* __restrict__ pred_disp,
    const float* __restrict__ targets,
    size_t b)
{
    float tg[NT];
#pragma unroll
    for (int t = 0; t < NT; ++t) {
        float v = targets[b * NT + t];
        tg[t] = (v == 0.0f) ? 1000000.0f : v;
    }
    float C[NQ];
    int   ind[NQ];
#pragma unroll
    for (int n = 0; n < NQ; ++n) {
        float d = pred_disp[b * NQ + n];
        float best = fabsf(d - tg[0]);
        int bi = 0;
#pragma unroll
        for (int t = 1; t < NT; ++t) {
            float e = fabsf(d - tg[t]);
            if (e < best) { best = e; bi = t; }   // strict <: first target wins
        }
        float sig = (float)(1.0 / (1.0 + exp(-(double)pred_logits[b * NQ + n])));
        C[n] = (-sig) + best;                     // same op order as reference
        ind[n] = bi;
    }
    unsigned mask = 0u;
#pragma unroll
    for (int t = 0; t < NT; ++t) {
        int w = 31;
        float bc = 3.0e38f;
#pragma unroll
        for (int n = 0; n < NQ; ++n) {
            bool upd = (ind[n] == t) && (C[n] < bc);  // strict <: first query wins
            bc = upd ? C[n] : bc;
            w  = upd ? n : w;
        }
        mask |= (1u << w);
    }
    return mask;
}

// FOUR lanes per row (proven layout: every global load/store is 16 B/lane
// perfectly contiguous). Lane j of a quad owns queries 4j..4j+3.
//
// Dedup is QUERY-CENTRIC: only per-target BEST keys are tracked (8 named
// scalars — never arrays, so nothing can be demoted to LDS/scratch),
// butterfly-reduced across the quad with DPP min. Each query then derives
// its label directly: label = (my key == best key of my target). The guard
// fires iff some non-winner query is within thr of its target's best —
// the 2nd-best query of a target has gap exactly bc2f-bcf, so this is
// equivalent to the validated (best,2nd-best) gap guard. need_slow is
// OR-reduced over the quad so the exact-path branch is quad-uniform.
__global__ __launch_bounds__(256) void nearest_matcher_kernel(
    const float* __restrict__ pred_logits,
    const float* __restrict__ pred_disp,
    const float* __restrict__ targets,
    float* __restrict__ out_idx,
    float* __restrict__ out_lab,
    int B)
{
    const size_t gid = (size_t)blockIdx.x * blockDim.x + threadIdx.x;
    const size_t b   = gid >> 2;          // row
    const int    j   = (int)(gid & 3);    // lane-in-quad: owns queries 4j..4j+3
    if (b >= (size_t)B) return;

    const float BIGF = 1000000.0f;

    // ---- coalesced loads: 16 B/lane, consecutive lanes consecutive addrs ----
    f32x4 d4 = ((const f32x4*)pred_disp)[gid];
    f32x4 l4 = ((const f32x4*)pred_logits)[gid];
    f32x4 t4 = ((const f32x4*)targets)[b * 2 + (size_t)(j & 1)];  // half (j&1)

    // sentinel-replace my half, then swap halves across lane^1 (DPP)
    float tv0 = (t4.x == 0.0f) ? BIGF : t4.x;
    float tv1 = (t4.y == 0.0f) ? BIGF : t4.y;
    float tv2 = (t4.z == 0.0f) ? BIGF : t4.z;
    float tv3 = (t4.w == 0.0f) ? BIGF : t4.w;
    float ov0 = dpp_xor1_f(tv0);
    float ov1 = dpp_xor1_f(tv1);
    float ov2 = dpp_xor1_f(tv2);
    float ov3 = dpp_xor1_f(tv3);

    const bool lo = ((j & 1) == 0);
    float tg[NT];
    tg[0] = lo ? tv0 : ov0;  tg[1] = lo ? tv1 : ov1;
    tg[2] = lo ? tv2 : ov2;  tg[3] = lo ? tv3 : ov3;
    tg[4] = lo ? ov0 : tv0;  tg[5] = lo ? ov1 : tv1;
    tg[6] = lo ? ov2 : tv2;  tg[7] = lo ? ov3 : tv3;

    // ---- my 4 queries: exact argmin over 8 targets + fast-sigmoid key ----
    int      ind[4];
    unsigned qk[4];
    {
        float dv[4] = {d4.x, d4.y, d4.z, d4.w};
        float lv[4] = {l4.x, l4.y, l4.z, l4.w};
#pragma unroll
        for (int i = 0; i < 4; ++i) {
            float d = dv[i];
            float best = fabsf(d - tg[0]);
            int bi = 0;
#pragma unroll
            for (int t = 1; t < NT; ++t) {
                float e = fabsf(d - tg[t]);
                if (e < best) { best = e; bi = t; }   // exact: matches reference
            }
            ind[i] = bi;
            float sig = __builtin_amdgcn_rcpf(1.0f + __expf(-lv[i]));
            float C = best - sig;
            int n = 4 * j + i;                        // global query id
            qk[i] = (ordf(C) & ~31u) | (unsigned)n;   // key: C order + query id
        }
    }

    // ---- per-target best over my 4 queries (min-only, named scalars) ----
    auto localbest = [&](int t) -> unsigned {
        unsigned bc = 0xFFFFFFFFu;
#pragma unroll
        for (int i = 0; i < 4; ++i) {
            unsigned x = (ind[i] == t) ? qk[i] : 0xFFFFFFFFu;
            bc = umin2(bc, x);
        }
        return bc;
    };
    unsigned bc0 = localbest(0), bc1 = localbest(1);
    unsigned bc2 = localbest(2), bc3 = localbest(3);
    unsigned bc4 = localbest(4), bc5 = localbest(5);
    unsigned bc6 = localbest(6), bc7 = localbest(7);

    // ---- butterfly min over the quad: 2 DPP + 2 min per target ----
    auto quadmin = [](unsigned v) -> unsigned {
        v = umin2(v, dpp_xor1_u(v));
        v = umin2(v, dpp_xor2_u(v));
        return v;
    };
    bc0 = quadmin(bc0); bc1 = quadmin(bc1);
    bc2 = quadmin(bc2); bc3 = quadmin(bc3);
    bc4 = quadmin(bc4); bc5 = quadmin(bc5);
    bc6 = quadmin(bc6); bc7 = quadmin(bc7);

    // ---- per-query label + guard ----
    // select bc[ind[i]] via 3-level cndmask tree (scalars only)
    auto selbc = [&](int id) -> unsigned {
        unsigned a0 = (id & 1) ? bc1 : bc0;
        unsigned a1 = (id & 1) ? bc3 : bc2;
        unsigned a2 = (id & 1) ? bc5 : bc4;
        unsigned a3 = (id & 1) ? bc7 : bc6;
        unsigned c0 = (id & 2) ? a1 : a0;
        unsigned c1 = (id & 2) ? a3 : a2;
        return (id & 4) ? c1 : c0;
    };

    bool  ns = false;
    float lab0, lab1, lab2, lab3;
    {
        float labs[4];
#pragma unroll
        for (int i = 0; i < 4; ++i) {
            unsigned bsel = selbc(ind[i]);
            bool isw = (qk[i] == bsel);
            // guard in float domain: non-winner within thr of its target's
            // best -> ambiguous under fast sigmoid + 5-bit key clearing.
            float Cf  = unordf(qk[i]);
            float bf  = unordf(bsel);
            float thr = fmaf(fabsf(bf), 1.6e-5f, 2.0e-4f);
            ns = ns || (!isw && ((Cf - bf) < thr));
            labs[i] = isw ? 1.0f : 0.0f;
        }
        lab0 = labs[0]; lab1 = labs[1]; lab2 = labs[2]; lab3 = labs[3];
    }

    // OR-reduce need_slow over the quad -> uniform branch, no divergence
    unsigned nsw = ns ? 1u : 0u;
    nsw |= dpp_xor1_u(nsw);
    nsw |= dpp_xor2_u(nsw);
    if (__builtin_expect(nsw != 0u, 0)) {
        unsigned mask = exact_mask(pred_logits, pred_disp, targets, b);
        lab0 = (float)((mask >> (4 * j + 0)) & 1u);
        lab1 = (float)((mask >> (4 * j + 1)) & 1u);
        lab2 = (float)((mask >> (4 * j + 2)) & 1u);
        lab3 = (float)((mask >> (4 * j + 3)) & 1u);
    }

    // ---- emit my 4 queries: 16 B/lane contiguous ----
    f32x4 oi, ol;
    oi.x = (float)ind[0]; oi.y = (float)ind[1];
    oi.z = (float)ind[2]; oi.w = (float)ind[3];
    ol.x = lab0; ol.y = lab1; ol.z = lab2; ol.w = lab3;
    ((f32x4*)out_idx)[gid] = oi;
    ((f32x4*)out_lab)[gid] = ol;
}

extern "C" void kernel_launch(void* const* d_in, const int* in_sizes, int n_in,
                              void* d_out, int out_size, void* d_ws, size_t ws_size,
                              hipStream_t stream) {
    const float* pred_logits = (const float*)d_in[0];
    const float* pred_disp   = (const float*)d_in[1];
    const float* targets     = (const float*)d_in[2];

    int B = in_sizes[0] / NQ;

    float* out_idx = (float*)d_out;              // indices [B, NQ] flat, first
    float* out_lab = out_idx + (size_t)B * NQ;   // labels  [B, NQ] flat, second

    const int threads = 256;
    const size_t total = (size_t)B * 4;          // 4 lanes per row
    const int blocks = (int)((total + threads - 1) / threads);
    hipLaunchKernelGGL(nearest_matcher_kernel, dim3(blocks), dim3(threads), 0, stream,
                       pred_logits, pred_disp, targets, out_idx, out_lab, B);
}